// Round 3
// baseline (300.447 us; speedup 1.0000x reference)
//
#include <hip/hip_runtime.h>

// Problem constants (fixed by setup_inputs()).
#define BATCH 32
#define HGT   1024
#define WID   1024
#define KREG  4
#define HALF  20   // SIZE/2, SIZE=40

#define SUM_BLOCKS 4096
#define SUM_THREADS 256
#define UNROLL 8   // n4 = 32*1024*1024/4 = 8388608 = 4096*256*8 exactly

__device__ __forceinline__ float wave_reduce_f(float v) {
    #pragma unroll
    for (int off = 32; off > 0; off >>= 1)
        v += __shfl_down(v, off, 64);
    return v;
}

__device__ __forceinline__ double wave_reduce_d(double v) {
    #pragma unroll
    for (int off = 32; off > 0; off >>= 1)
        v += __shfl_down(v, off, 64);
    return v;
}

// ---------------------------------------------------------------------------
// Kernel 1: global partial sums (SoA): part[b], part[NB+b], part[2*NB+b]
//           = blockwise sum(P*G), sum(P), sum(G)
// __launch_bounds__(256, 2): min 2 waves/EU -> VGPR cap 256, so the
// scheduler can keep all 16 dwordx4 loads in flight (VGPR=36 last round
// proved it was batching ~5 at a time).
// ---------------------------------------------------------------------------
__global__ __launch_bounds__(SUM_THREADS, 2) void global_sums_kernel(
        const float4* __restrict__ p, const float4* __restrict__ g,
        float* __restrict__ part) {
    const long stride = (long)SUM_BLOCKS * SUM_THREADS;
    const long base   = (long)blockIdx.x * SUM_THREADS + threadIdx.x;

    float4 a[UNROLL], b[UNROLL];
    #pragma unroll
    for (int j = 0; j < UNROLL; ++j) a[j] = p[base + (long)j * stride];
    #pragma unroll
    for (int j = 0; j < UNROLL; ++j) b[j] = g[base + (long)j * stride];

#if defined(__has_builtin)
#if __has_builtin(__builtin_amdgcn_sched_barrier)
    __builtin_amdgcn_sched_barrier(0);  // keep all loads issued before math
#endif
#endif

    float sp = 0.f, sg = 0.f, spg = 0.f;
    #pragma unroll
    for (int j = 0; j < UNROLL; ++j) {
        sp  += (a[j].x + a[j].y) + (a[j].z + a[j].w);
        sg  += (b[j].x + b[j].y) + (b[j].z + b[j].w);
        spg += (a[j].x * b[j].x + a[j].y * b[j].y)
             + (a[j].z * b[j].z + a[j].w * b[j].w);
    }

    spg = wave_reduce_f(spg);
    sp  = wave_reduce_f(sp);
    sg  = wave_reduce_f(sg);

    __shared__ float smem[3][4];
    int lane = threadIdx.x & 63;
    int wv   = threadIdx.x >> 6;
    if (lane == 0) { smem[0][wv] = spg; smem[1][wv] = sp; smem[2][wv] = sg; }
    __syncthreads();
    if (threadIdx.x == 0) {
        float tpg = 0.f, tp = 0.f, tg = 0.f;
        #pragma unroll
        for (int w = 0; w < SUM_THREADS / 64; ++w) {
            tpg += smem[0][w]; tp += smem[1][w]; tg += smem[2][w];
        }
        part[blockIdx.x]                  = tpg;
        part[SUM_BLOCKS + blockIdx.x]     = tp;
        part[2 * SUM_BLOCKS + blockIdx.x] = tg;
    }
}

// ---------------------------------------------------------------------------
// Kernel 2: per-region soft IoU -> ious[r], one block per (b,k) region.
// Wave-per-row mapping: lane = column (w <= 40 < 64), wave strides rows.
// Coalesced 160B row reads, no integer division.
// ---------------------------------------------------------------------------
__device__ __forceinline__ void region_bounds(int c, int dim, int& s, int& e) {
    s = max(c - HALF, 0);
    e = min(c + HALF, dim);
    int n = e - s;
    bool odd_small = ((n & 1) != 0) && (n < 2 * HALF);
    if (odd_small && s == 0) e -= 1;
    if (odd_small && e == dim) s += 1;
}

__global__ __launch_bounds__(256) void region_iou_kernel(
        const float* __restrict__ p, const float* __restrict__ g,
        const int* __restrict__ cents, float* __restrict__ ious) {
    int r = blockIdx.x;            // 0 .. BATCH*KREG-1
    int b = r / KREG;
    int cy = cents[r * 2 + 0];
    int cx = cents[r * 2 + 1];

    int sy, ey, sx, ex;
    region_bounds(cy, HGT, sy, ey);
    region_bounds(cx, WID, sx, ex);
    int w = ex - sx;

    const float* pb = p + (size_t)b * HGT * WID;
    const float* gb = g + (size_t)b * HGT * WID;

    int lane = threadIdx.x & 63;
    int wv   = threadIdx.x >> 6;

    float sp = 0.f, sg = 0.f, spg = 0.f;
    if (lane < w) {
        for (int yy = sy + wv; yy < ey; yy += 4) {
            size_t off = (size_t)yy * WID + sx + lane;
            float pv = pb[off];
            float gv = gb[off];
            sp  += pv;
            sg  += gv;
            spg += pv * gv;
        }
    }
    spg = wave_reduce_f(spg);
    sp  = wave_reduce_f(sp);
    sg  = wave_reduce_f(sg);

    __shared__ float smem[3][4];
    if (lane == 0) { smem[0][wv] = spg; smem[1][wv] = sp; smem[2][wv] = sg; }
    __syncthreads();
    if (threadIdx.x == 0) {
        float tpg = 0.f, tp = 0.f, tg = 0.f;
        #pragma unroll
        for (int w2 = 0; w2 < 4; ++w2) {
            tpg += smem[0][w2]; tp += smem[1][w2]; tg += smem[2][w2];
        }
        ious[r] = (tpg + 1.0f) / (tp + tg - tpg + 1.0f);
    }
}

// ---------------------------------------------------------------------------
// Kernel 3: finalize — reduce partials (double) and compute scalar loss.
// ---------------------------------------------------------------------------
__global__ __launch_bounds__(256) void finalize_kernel(
        const float4* __restrict__ part4, const float* __restrict__ ious,
        float* __restrict__ out) {
    const int Q = SUM_BLOCKS / 4;   // 1024 float4 per quantity
    double spg = 0.0, sp = 0.0, sg = 0.0, siou = 0.0;
    for (int i = threadIdx.x; i < Q; i += 256) {
        float4 v0 = part4[i];
        float4 v1 = part4[Q + i];
        float4 v2 = part4[2 * Q + i];
        spg += (double)((v0.x + v0.y) + (v0.z + v0.w));
        sp  += (double)((v1.x + v1.y) + (v1.z + v1.w));
        sg  += (double)((v2.x + v2.y) + (v2.z + v2.w));
    }
    if (threadIdx.x < BATCH * KREG) siou = (double)ious[threadIdx.x];

    spg  = wave_reduce_d(spg);
    sp   = wave_reduce_d(sp);
    sg   = wave_reduce_d(sg);
    siou = wave_reduce_d(siou);

    __shared__ double smem[4][4];
    int lane = threadIdx.x & 63;
    int wv   = threadIdx.x >> 6;
    if (lane == 0) {
        smem[0][wv] = spg; smem[1][wv] = sp; smem[2][wv] = sg; smem[3][wv] = siou;
    }
    __syncthreads();
    if (threadIdx.x == 0) {
        double tpg = 0.0, tp = 0.0, tg = 0.0, ti = 0.0;
        #pragma unroll
        for (int w = 0; w < 4; ++w) {
            tpg += smem[0][w]; tp += smem[1][w]; tg += smem[2][w]; ti += smem[3][w];
        }
        double loss_global = 1.0 - (tpg + 1.0) / (tp + tg - tpg + 1.0);
        double loss_region = 1.0 - ti / (double)(BATCH * KREG);
        out[0] = (float)(loss_global + loss_region);
    }
}

extern "C" void kernel_launch(void* const* d_in, const int* in_sizes, int n_in,
                              void* d_out, int out_size, void* d_ws, size_t ws_size,
                              hipStream_t stream) {
    const float* preds = (const float*)d_in[0];
    const float* gt    = (const float*)d_in[1];
    const int*   cents = (const int*)d_in[2];
    float* out = (float*)d_out;

    float* part = (float*)d_ws;                       // 3*SUM_BLOCKS floats
    float* ious = part + 3 * SUM_BLOCKS;              // BATCH*KREG floats

    global_sums_kernel<<<SUM_BLOCKS, SUM_THREADS, 0, stream>>>(
        (const float4*)preds, (const float4*)gt, part);
    region_iou_kernel<<<BATCH * KREG, 256, 0, stream>>>(preds, gt, cents, ious);
    finalize_kernel<<<1, 256, 0, stream>>>((const float4*)part, ious, out);
}

// Round 4
// 288.683 us; speedup vs baseline: 1.0408x; 1.0408x over previous
//
#include <hip/hip_runtime.h>

// Problem constants (fixed by setup_inputs()).
#define BATCH 32
#define HGT   1024
#define WID   1024
#define KREG  4
#define HALF  20   // SIZE/2, SIZE=40

#define SUM_BLOCKS 4096
#define SUM_THREADS 256
#define UNROLL 8   // n4 = 32*1024*1024/4 = 8388608 = 4096*256*8 exactly

__device__ __forceinline__ float wave_reduce_f(float v) {
    #pragma unroll
    for (int off = 32; off > 0; off >>= 1)
        v += __shfl_down(v, off, 64);
    return v;
}

__device__ __forceinline__ double wave_reduce_d(double v) {
    #pragma unroll
    for (int off = 32; off > 0; off >>= 1)
        v += __shfl_down(v, off, 64);
    return v;
}

// ---------------------------------------------------------------------------
// Kernel 1: global partial sums (SoA): part[b], part[NB+b], part[2*NB+b]
//           = blockwise sum(P*G), sum(P), sum(G)
// __syncthreads() between the 16 loads and the math: global loads cannot
// sink across a block barrier, so all 16 dwordx4 loads MUST be issued
// back-to-back with all dest regs live (VGPR >= ~80 is the signature).
// This forces per-wave MLP = 16; R1->R2 showed dur scales with in-flight.
// ---------------------------------------------------------------------------
__global__ __launch_bounds__(SUM_THREADS) void global_sums_kernel(
        const float4* __restrict__ p, const float4* __restrict__ g,
        float* __restrict__ part) {
    const long stride = (long)SUM_BLOCKS * SUM_THREADS;
    const long base   = (long)blockIdx.x * SUM_THREADS + threadIdx.x;

    float4 a[UNROLL], b[UNROLL];
    #pragma unroll
    for (int j = 0; j < UNROLL; ++j) a[j] = p[base + (long)j * stride];
    #pragma unroll
    for (int j = 0; j < UNROLL; ++j) b[j] = g[base + (long)j * stride];

    __syncthreads();   // hard fence: all 16 loads issued & live before math

    float sp = 0.f, sg = 0.f, spg = 0.f;
    #pragma unroll
    for (int j = 0; j < UNROLL; ++j) {
        sp  += (a[j].x + a[j].y) + (a[j].z + a[j].w);
        sg  += (b[j].x + b[j].y) + (b[j].z + b[j].w);
        spg += (a[j].x * b[j].x + a[j].y * b[j].y)
             + (a[j].z * b[j].z + a[j].w * b[j].w);
    }

    spg = wave_reduce_f(spg);
    sp  = wave_reduce_f(sp);
    sg  = wave_reduce_f(sg);

    __shared__ float smem[3][4];
    int lane = threadIdx.x & 63;
    int wv   = threadIdx.x >> 6;
    if (lane == 0) { smem[0][wv] = spg; smem[1][wv] = sp; smem[2][wv] = sg; }
    __syncthreads();
    if (threadIdx.x == 0) {
        float tpg = 0.f, tp = 0.f, tg = 0.f;
        #pragma unroll
        for (int w = 0; w < SUM_THREADS / 64; ++w) {
            tpg += smem[0][w]; tp += smem[1][w]; tg += smem[2][w];
        }
        part[blockIdx.x]                  = tpg;
        part[SUM_BLOCKS + blockIdx.x]     = tp;
        part[2 * SUM_BLOCKS + blockIdx.x] = tg;
    }
}

// ---------------------------------------------------------------------------
// Kernel 2: per-region soft IoU -> ious[r], one block per (b,k) region.
// Wave-per-row mapping: lane = column (w <= 40 < 64), wave strides rows.
// ---------------------------------------------------------------------------
__device__ __forceinline__ void region_bounds(int c, int dim, int& s, int& e) {
    s = max(c - HALF, 0);
    e = min(c + HALF, dim);
    int n = e - s;
    bool odd_small = ((n & 1) != 0) && (n < 2 * HALF);
    if (odd_small && s == 0) e -= 1;
    if (odd_small && e == dim) s += 1;
}

__global__ __launch_bounds__(256) void region_iou_kernel(
        const float* __restrict__ p, const float* __restrict__ g,
        const int* __restrict__ cents, float* __restrict__ ious) {
    int r = blockIdx.x;            // 0 .. BATCH*KREG-1
    int b = r / KREG;
    int cy = cents[r * 2 + 0];
    int cx = cents[r * 2 + 1];

    int sy, ey, sx, ex;
    region_bounds(cy, HGT, sy, ey);
    region_bounds(cx, WID, sx, ex);
    int w = ex - sx;

    const float* pb = p + (size_t)b * HGT * WID;
    const float* gb = g + (size_t)b * HGT * WID;

    int lane = threadIdx.x & 63;
    int wv   = threadIdx.x >> 6;

    float sp = 0.f, sg = 0.f, spg = 0.f;
    if (lane < w) {
        for (int yy = sy + wv; yy < ey; yy += 4) {
            size_t off = (size_t)yy * WID + sx + lane;
            float pv = pb[off];
            float gv = gb[off];
            sp  += pv;
            sg  += gv;
            spg += pv * gv;
        }
    }
    spg = wave_reduce_f(spg);
    sp  = wave_reduce_f(sp);
    sg  = wave_reduce_f(sg);

    __shared__ float smem[3][4];
    if (lane == 0) { smem[0][wv] = spg; smem[1][wv] = sp; smem[2][wv] = sg; }
    __syncthreads();
    if (threadIdx.x == 0) {
        float tpg = 0.f, tp = 0.f, tg = 0.f;
        #pragma unroll
        for (int w2 = 0; w2 < 4; ++w2) {
            tpg += smem[0][w2]; tp += smem[1][w2]; tg += smem[2][w2];
        }
        ious[r] = (tpg + 1.0f) / (tp + tg - tpg + 1.0f);
    }
}

// ---------------------------------------------------------------------------
// Kernel 3: finalize — reduce partials (double) and compute scalar loss.
// ---------------------------------------------------------------------------
__global__ __launch_bounds__(256) void finalize_kernel(
        const float4* __restrict__ part4, const float* __restrict__ ious,
        float* __restrict__ out) {
    const int Q = SUM_BLOCKS / 4;   // 1024 float4 per quantity
    double spg = 0.0, sp = 0.0, sg = 0.0, siou = 0.0;
    for (int i = threadIdx.x; i < Q; i += 256) {
        float4 v0 = part4[i];
        float4 v1 = part4[Q + i];
        float4 v2 = part4[2 * Q + i];
        spg += (double)((v0.x + v0.y) + (v0.z + v0.w));
        sp  += (double)((v1.x + v1.y) + (v1.z + v1.w));
        sg  += (double)((v2.x + v2.y) + (v2.z + v2.w));
    }
    if (threadIdx.x < BATCH * KREG) siou = (double)ious[threadIdx.x];

    spg  = wave_reduce_d(spg);
    sp   = wave_reduce_d(sp);
    sg   = wave_reduce_d(sg);
    siou = wave_reduce_d(siou);

    __shared__ double smem[4][4];
    int lane = threadIdx.x & 63;
    int wv   = threadIdx.x >> 6;
    if (lane == 0) {
        smem[0][wv] = spg; smem[1][wv] = sp; smem[2][wv] = sg; smem[3][wv] = siou;
    }
    __syncthreads();
    if (threadIdx.x == 0) {
        double tpg = 0.0, tp = 0.0, tg = 0.0, ti = 0.0;
        #pragma unroll
        for (int w = 0; w < 4; ++w) {
            tpg += smem[0][w]; tp += smem[1][w]; tg += smem[2][w]; ti += smem[3][w];
        }
        double loss_global = 1.0 - (tpg + 1.0) / (tp + tg - tpg + 1.0);
        double loss_region = 1.0 - ti / (double)(BATCH * KREG);
        out[0] = (float)(loss_global + loss_region);
    }
}

extern "C" void kernel_launch(void* const* d_in, const int* in_sizes, int n_in,
                              void* d_out, int out_size, void* d_ws, size_t ws_size,
                              hipStream_t stream) {
    const float* preds = (const float*)d_in[0];
    const float* gt    = (const float*)d_in[1];
    const int*   cents = (const int*)d_in[2];
    float* out = (float*)d_out;

    float* part = (float*)d_ws;                       // 3*SUM_BLOCKS floats
    float* ious = part + 3 * SUM_BLOCKS;              // BATCH*KREG floats

    global_sums_kernel<<<SUM_BLOCKS, SUM_THREADS, 0, stream>>>(
        (const float4*)preds, (const float4*)gt, part);
    region_iou_kernel<<<BATCH * KREG, 256, 0, stream>>>(preds, gt, cents, ious);
    finalize_kernel<<<1, 256, 0, stream>>>((const float4*)part, ious, out);
}

// Round 5
// 275.885 us; speedup vs baseline: 1.0890x; 1.0464x over previous
//
#include <hip/hip_runtime.h>

// Problem constants (fixed by setup_inputs()).
#define BATCH 32
#define HGT   1024
#define WID   1024
#define KREG  4
#define HALF  20   // SIZE/2, SIZE=40

#define SUM_BLOCKS 4096       // total across both half-kernels
#define HALF_BLOCKS (SUM_BLOCKS / 2)
#define SUM_THREADS 256
#define UNROLL 8   // n4 = 8388608 = 4096*256*8 exactly

typedef float f32x4 __attribute__((ext_vector_type(4)));

__device__ __forceinline__ float wave_reduce_f(float v) {
    #pragma unroll
    for (int off = 32; off > 0; off >>= 1)
        v += __shfl_down(v, off, 64);
    return v;
}

__device__ __forceinline__ double wave_reduce_d(double v) {
    #pragma unroll
    for (int off = 32; off > 0; off >>= 1)
        v += __shfl_down(v, off, 64);
    return v;
}

// ---------------------------------------------------------------------------
// Shared tail: block reduce 3 quantities and write SoA partials.
// ---------------------------------------------------------------------------
__device__ __forceinline__ void block_reduce_store(
        float spg, float sp, float sg, float* __restrict__ part, int slot) {
    spg = wave_reduce_f(spg);
    sp  = wave_reduce_f(sp);
    sg  = wave_reduce_f(sg);
    __shared__ float smem[3][4];
    int lane = threadIdx.x & 63;
    int wv   = threadIdx.x >> 6;
    if (lane == 0) { smem[0][wv] = spg; smem[1][wv] = sp; smem[2][wv] = sg; }
    __syncthreads();
    if (threadIdx.x == 0) {
        float tpg = 0.f, tp = 0.f, tg = 0.f;
        #pragma unroll
        for (int w = 0; w < SUM_THREADS / 64; ++w) {
            tpg += smem[0][w]; tp += smem[1][w]; tg += smem[2][w];
        }
        part[slot]                  = tpg;
        part[SUM_BLOCKS + slot]     = tp;
        part[2 * SUM_BLOCKS + slot] = tg;
    }
}

// ---------------------------------------------------------------------------
// Variant A: nontemporal loads (nt flag -> bypass L1 fill tracking).
// Handles elements [0, n4/2).
// ---------------------------------------------------------------------------
__global__ __launch_bounds__(SUM_THREADS) void global_sums_nt_kernel(
        const f32x4* __restrict__ p, const f32x4* __restrict__ g,
        float* __restrict__ part) {
    const long stride = (long)HALF_BLOCKS * SUM_THREADS;
    const long base   = (long)blockIdx.x * SUM_THREADS + threadIdx.x;

    f32x4 a[UNROLL], b[UNROLL];
    #pragma unroll
    for (int j = 0; j < UNROLL; ++j)
        a[j] = __builtin_nontemporal_load(&p[base + (long)j * stride]);
    #pragma unroll
    for (int j = 0; j < UNROLL; ++j)
        b[j] = __builtin_nontemporal_load(&g[base + (long)j * stride]);

    float sp = 0.f, sg = 0.f, spg = 0.f;
    #pragma unroll
    for (int j = 0; j < UNROLL; ++j) {
        sp  += (a[j].x + a[j].y) + (a[j].z + a[j].w);
        sg  += (b[j].x + b[j].y) + (b[j].z + b[j].w);
        spg += (a[j].x * b[j].x + a[j].y * b[j].y)
             + (a[j].z * b[j].z + a[j].w * b[j].w);
    }
    block_reduce_store(spg, sp, sg, part, blockIdx.x);
}

// ---------------------------------------------------------------------------
// Variant B: plain loads (control). Handles elements [n4/2, n4).
// ---------------------------------------------------------------------------
__global__ __launch_bounds__(SUM_THREADS) void global_sums_reg_kernel(
        const f32x4* __restrict__ p, const f32x4* __restrict__ g,
        float* __restrict__ part) {
    const long stride = (long)HALF_BLOCKS * SUM_THREADS;
    const long half_off = (long)HALF_BLOCKS * SUM_THREADS * UNROLL;
    const long base   = half_off + (long)blockIdx.x * SUM_THREADS + threadIdx.x;

    f32x4 a[UNROLL], b[UNROLL];
    #pragma unroll
    for (int j = 0; j < UNROLL; ++j) a[j] = p[base + (long)j * stride];
    #pragma unroll
    for (int j = 0; j < UNROLL; ++j) b[j] = g[base + (long)j * stride];

    float sp = 0.f, sg = 0.f, spg = 0.f;
    #pragma unroll
    for (int j = 0; j < UNROLL; ++j) {
        sp  += (a[j].x + a[j].y) + (a[j].z + a[j].w);
        sg  += (b[j].x + b[j].y) + (b[j].z + b[j].w);
        spg += (a[j].x * b[j].x + a[j].y * b[j].y)
             + (a[j].z * b[j].z + a[j].w * b[j].w);
    }
    block_reduce_store(spg, sp, sg, part, HALF_BLOCKS + blockIdx.x);
}

// ---------------------------------------------------------------------------
// Kernel 2: per-region soft IoU -> ious[r], one block per (b,k) region.
// ---------------------------------------------------------------------------
__device__ __forceinline__ void region_bounds(int c, int dim, int& s, int& e) {
    s = max(c - HALF, 0);
    e = min(c + HALF, dim);
    int n = e - s;
    bool odd_small = ((n & 1) != 0) && (n < 2 * HALF);
    if (odd_small && s == 0) e -= 1;
    if (odd_small && e == dim) s += 1;
}

__global__ __launch_bounds__(256) void region_iou_kernel(
        const float* __restrict__ p, const float* __restrict__ g,
        const int* __restrict__ cents, float* __restrict__ ious) {
    int r = blockIdx.x;            // 0 .. BATCH*KREG-1
    int b = r / KREG;
    int cy = cents[r * 2 + 0];
    int cx = cents[r * 2 + 1];

    int sy, ey, sx, ex;
    region_bounds(cy, HGT, sy, ey);
    region_bounds(cx, WID, sx, ex);
    int w = ex - sx;

    const float* pb = p + (size_t)b * HGT * WID;
    const float* gb = g + (size_t)b * HGT * WID;

    int lane = threadIdx.x & 63;
    int wv   = threadIdx.x >> 6;

    float sp = 0.f, sg = 0.f, spg = 0.f;
    if (lane < w) {
        for (int yy = sy + wv; yy < ey; yy += 4) {
            size_t off = (size_t)yy * WID + sx + lane;
            float pv = pb[off];
            float gv = gb[off];
            sp  += pv;
            sg  += gv;
            spg += pv * gv;
        }
    }
    spg = wave_reduce_f(spg);
    sp  = wave_reduce_f(sp);
    sg  = wave_reduce_f(sg);

    __shared__ float smem[3][4];
    if (lane == 0) { smem[0][wv] = spg; smem[1][wv] = sp; smem[2][wv] = sg; }
    __syncthreads();
    if (threadIdx.x == 0) {
        float tpg = 0.f, tp = 0.f, tg = 0.f;
        #pragma unroll
        for (int w2 = 0; w2 < 4; ++w2) {
            tpg += smem[0][w2]; tp += smem[1][w2]; tg += smem[2][w2];
        }
        ious[r] = (tpg + 1.0f) / (tp + tg - tpg + 1.0f);
    }
}

// ---------------------------------------------------------------------------
// Kernel 3: finalize — reduce partials (double) and compute scalar loss.
// ---------------------------------------------------------------------------
__global__ __launch_bounds__(256) void finalize_kernel(
        const float4* __restrict__ part4, const float* __restrict__ ious,
        float* __restrict__ out) {
    const int Q = SUM_BLOCKS / 4;   // 1024 float4 per quantity
    double spg = 0.0, sp = 0.0, sg = 0.0, siou = 0.0;
    for (int i = threadIdx.x; i < Q; i += 256) {
        float4 v0 = part4[i];
        float4 v1 = part4[Q + i];
        float4 v2 = part4[2 * Q + i];
        spg += (double)((v0.x + v0.y) + (v0.z + v0.w));
        sp  += (double)((v1.x + v1.y) + (v1.z + v1.w));
        sg  += (double)((v2.x + v2.y) + (v2.z + v2.w));
    }
    if (threadIdx.x < BATCH * KREG) siou = (double)ious[threadIdx.x];

    spg  = wave_reduce_d(spg);
    sp   = wave_reduce_d(sp);
    sg   = wave_reduce_d(sg);
    siou = wave_reduce_d(siou);

    __shared__ double smem[4][4];
    int lane = threadIdx.x & 63;
    int wv   = threadIdx.x >> 6;
    if (lane == 0) {
        smem[0][wv] = spg; smem[1][wv] = sp; smem[2][wv] = sg; smem[3][wv] = siou;
    }
    __syncthreads();
    if (threadIdx.x == 0) {
        double tpg = 0.0, tp = 0.0, tg = 0.0, ti = 0.0;
        #pragma unroll
        for (int w = 0; w < 4; ++w) {
            tpg += smem[0][w]; tp += smem[1][w]; tg += smem[2][w]; ti += smem[3][w];
        }
        double loss_global = 1.0 - (tpg + 1.0) / (tp + tg - tpg + 1.0);
        double loss_region = 1.0 - ti / (double)(BATCH * KREG);
        out[0] = (float)(loss_global + loss_region);
    }
}

extern "C" void kernel_launch(void* const* d_in, const int* in_sizes, int n_in,
                              void* d_out, int out_size, void* d_ws, size_t ws_size,
                              hipStream_t stream) {
    const float* preds = (const float*)d_in[0];
    const float* gt    = (const float*)d_in[1];
    const int*   cents = (const int*)d_in[2];
    float* out = (float*)d_out;

    float* part = (float*)d_ws;                       // 3*SUM_BLOCKS floats
    float* ious = part + 3 * SUM_BLOCKS;              // BATCH*KREG floats

    global_sums_nt_kernel<<<HALF_BLOCKS, SUM_THREADS, 0, stream>>>(
        (const f32x4*)preds, (const f32x4*)gt, part);
    global_sums_reg_kernel<<<HALF_BLOCKS, SUM_THREADS, 0, stream>>>(
        (const f32x4*)preds, (const f32x4*)gt, part);
    region_iou_kernel<<<BATCH * KREG, 256, 0, stream>>>(preds, gt, cents, ious);
    finalize_kernel<<<1, 256, 0, stream>>>((const float4*)part, ious, out);
}